// Round 5
// baseline (3693.845 us; speedup 1.0000x reference)
//
#include <hip/hip_runtime.h>

// QLSTM: T=512, B=64, D=512, H=512.
// Phase A: precompute gx[tb][2560] = bf16( X@[Wx|Wr]^T + bias )  (gates x-part + residual)
// Phase B: persistent 32-block kernel, 512 steps.
//   R2: agent-scope atomics for the handoff (replaced __threadfence).
//   R3: S padded [.][64][20] to kill ds_write bank conflicts.
//   R7: K-split across waves (proven: conflicts -20%, time flat -> LDS not
//       on critical path; handoff latency is).
//   R8: DELETE the LDS h-staging. Every wave's A-fragments are disjoint 16B
//       chunks of h (no cross-wave reuse), so each lane loads its exact MFMA
//       fragments DIRECTLY global->register (16x dwordx4 sc0 sc1, imm offsets
//       off 2 bases, one drain). Removes 16 ds_writes + a barrier + 16
//       ds_reads from the serial chain. Block widened to 512 thr / 8 waves
//       (gate-half x K-half x batch-half): resident Bf 128->64 VGPR so the
//       16 in-flight fragments fit comfortably; 2 waves/SIMD hides latency.
//       gx prefetch double-buffered + issued right after the frag drain so
//       the next poll's vmcnt(0) doesn't eat an HBM round trip.
//       Sync protocol byte-identical to R0/R7.

typedef __bf16         bfrag8 __attribute__((ext_vector_type(8)));
typedef float          f32x4v __attribute__((ext_vector_type(4)));
typedef unsigned short u16x8  __attribute__((ext_vector_type(8)));
typedef int            v4i    __attribute__((ext_vector_type(4)));

#define N_TB    32768   // T*B
#define GXW     2560    // 4*512 gate rows + 512 residual rows
#define OUT_HX  16777216
#define OUT_CX  16809984

__device__ __forceinline__ float bf2f(unsigned short u) {
  unsigned int x = ((unsigned int)u) << 16;
  return __builtin_bit_cast(float, x);
}
__device__ __forceinline__ unsigned short f2bf(float f) {
  unsigned int x = __builtin_bit_cast(unsigned int, f);
  x = x + 0x7FFFu + ((x >> 16) & 1u);   // RNE
  return (unsigned short)(x >> 16);
}
__device__ __forceinline__ float sigf(float x) {
  x = fminf(fmaxf(x, -30.f), 30.f);
  return 1.f / (1.f + __expf(-x));
}
__device__ __forceinline__ float tanh_f(float x) {
  x = fminf(fmaxf(x, -15.f), 15.f);
  float e = __expf(-2.f * x);
  return (1.f - e) / (1.f + e);
}

// ---------- K1: f32 -> bf16 convert (inputs -> X) ----------
__global__ void cvt_kernel(const float* __restrict__ in, unsigned short* __restrict__ out) {
  int i = (blockIdx.x * 256 + threadIdx.x) * 4;
  float4 v = *(const float4*)(in + i);
  ushort4 o = make_ushort4(f2bf(v.x), f2bf(v.y), f2bf(v.z), f2bf(v.w));
  *(ushort4*)(out + i) = o;
}

// ---------- K2: weight repack f32->bf16 ----------
__global__ void repack_kernel(const float* __restrict__ Wf, const float* __restrict__ Wi,
                              const float* __restrict__ Wg, const float* __restrict__ Wo,
                              const float* __restrict__ Wr,
                              const float* __restrict__ bfp, const float* __restrict__ bip,
                              const float* __restrict__ bgp, const float* __restrict__ bop,
                              const float* __restrict__ brp,
                              unsigned short* __restrict__ Wc, unsigned short* __restrict__ Whx,
                              float* __restrict__ bias) {
  int tid = blockIdx.x * 256 + threadIdx.x;
  if (tid < 262144) {                    // gate rows: 2048 rows x 128 quads
    int row = tid >> 7;
    int k4  = (tid & 127) * 4;
    int g = row >> 9, h = row & 511;
    const float* W = (g == 0) ? Wf : (g == 1) ? Wi : (g == 2) ? Wg : Wo;
    float4 a = *(const float4*)(W + (size_t)h * 1024 + k4);
    float4 b = *(const float4*)(W + (size_t)h * 1024 + 512 + k4);
    *(ushort4*)(Wc  + (size_t)row * 512 + k4) = make_ushort4(f2bf(a.x), f2bf(a.y), f2bf(a.z), f2bf(a.w));
    *(ushort4*)(Whx + (size_t)row * 512 + k4) = make_ushort4(f2bf(b.x), f2bf(b.y), f2bf(b.z), f2bf(b.w));
  } else if (tid < 327680) {             // residual rows
    int t2 = tid - 262144;
    int row = t2 >> 7;
    int k4  = (t2 & 127) * 4;
    float4 a = *(const float4*)(Wr + (size_t)row * 512 + k4);
    *(ushort4*)(Wc + (size_t)(2048 + row) * 512 + k4) =
        make_ushort4(f2bf(a.x), f2bf(a.y), f2bf(a.z), f2bf(a.w));
  }
  if (tid < 2560) {
    float v;
    if      (tid <  512) v = bfp[tid];
    else if (tid < 1024) v = bip[tid - 512];
    else if (tid < 1536) v = bgp[tid - 1024];
    else if (tid < 2048) v = bop[tid - 1536];
    else                 v = brp[tid - 2048];
    bias[tid] = v;
  }
}

// ---------- K3: GEMM  C[n][m] = bf16( sum_k A[m][k]*B[n][k] + bias[m] ) ----------
__global__ __launch_bounds__(256)
void gemm_kernel(const unsigned short* __restrict__ A, const unsigned short* __restrict__ B,
                 const float* __restrict__ bias, unsigned short* __restrict__ C) {
  const int bm = blockIdx.x;       // 0..19
  const int bn = blockIdx.y;       // 0..255
  const int tid = threadIdx.x;
  const int lane = tid & 63;
  const int w = tid >> 6;
  const int wm = w & 1, wn = w >> 1;
  const int col = lane & 15, q = lane >> 4;

  __shared__ unsigned short As[128 * 64] __attribute__((aligned(16)));
  __shared__ unsigned short Bs[128 * 64] __attribute__((aligned(16)));

  f32x4v acc[4][4] = {};

  for (int kt = 0; kt < 8; ++kt) {
    __syncthreads();
    #pragma unroll
    for (int p = 0; p < 4; ++p) {
      int idx = p * 256 + tid;          // 16B granule id
      int row = idx >> 3, gc = idx & 7;
      *(u16x8*)(&As[idx * 8]) = *(const u16x8*)(A + (size_t)(bm * 128 + row) * 512 + kt * 64 + gc * 8);
      *(u16x8*)(&Bs[idx * 8]) = *(const u16x8*)(B + (size_t)(bn * 128 + row) * 512 + kt * 64 + gc * 8);
    }
    __syncthreads();
    #pragma unroll
    for (int kk = 0; kk < 2; ++kk) {
      bfrag8 af[4], bfr[4];
      #pragma unroll
      for (int mt = 0; mt < 4; ++mt)
        af[mt] = *(const bfrag8*)(&As[(wm * 64 + mt * 16 + col) * 64 + kk * 32 + q * 8]);
      #pragma unroll
      for (int nt = 0; nt < 4; ++nt)
        bfr[nt] = *(const bfrag8*)(&Bs[(wn * 64 + nt * 16 + col) * 64 + kk * 32 + q * 8]);
      #pragma unroll
      for (int mt = 0; mt < 4; ++mt)
        #pragma unroll
        for (int nt = 0; nt < 4; ++nt)
          acc[mt][nt] = __builtin_amdgcn_mfma_f32_16x16x32_bf16(af[mt], bfr[nt], acc[mt][nt], 0, 0, 0);
    }
  }
  #pragma unroll
  for (int mt = 0; mt < 4; ++mt) {
    const int m0 = bm * 128 + wm * 64 + mt * 16 + q * 4;
    const float4 b4 = *(const float4*)(bias + m0);
    #pragma unroll
    for (int nt = 0; nt < 4; ++nt) {
      const int n = bn * 128 + wn * 64 + nt * 16 + col;
      f32x4v v = acc[mt][nt];
      ushort4 o = make_ushort4(f2bf(v[0] + b4.x), f2bf(v[1] + b4.y),
                               f2bf(v[2] + b4.z), f2bf(v[3] + b4.w));
      *(ushort4*)(C + (size_t)n * GXW + m0) = o;
    }
  }
}

// ---------- K4: persistent recurrent kernel ----------
// 32 blocks x 512 threads (8 waves). Block jb owns h_out [jb*16, jb*16+16).
// Wave w: gh=w&1 (gate half), gp=(w>>1)&1 (K half), mh=w>>2 (batch half).
__global__ __launch_bounds__(512, 1)
void recur_kernel(const unsigned short* __restrict__ Whx, const unsigned short* __restrict__ gx,
                  unsigned short* __restrict__ hbuf, int* flags, float* __restrict__ out) {
  const int jb = blockIdx.x;
  const int tid = threadIdx.x;
  const int lane = tid & 63;
  const int w = tid >> 6;        // 0..7
  const int gh = w & 1;          // gate half
  const int gp = (w >> 1) & 1;   // K half
  const int mh = w >> 2;         // batch half
  const int col = lane & 15;
  const int q = lane >> 4;

  __shared__ float S[2][4][64][20] __attribute__((aligned(16)));  // [K-half][gate][b][col]

  // Resident B fragments: 2 gates x 8 k-tiles (this wave's gate/K quarter).
  bfrag8 Bf[2][8];
  #pragma unroll
  for (int g2 = 0; g2 < 2; ++g2) {
    const int gate = gh * 2 + g2;
    const unsigned short* wp = Whx + (size_t)(gate * 512 + jb * 16 + col) * 512 + gp * 256 + q * 8;
    #pragma unroll
    for (int kk = 0; kk < 8; ++kk)
      Bf[g2][kk] = *(const bfrag8*)(wp + kk * 32);
  }

  // Update-phase mapping: thread -> (batch ub, 2 cols starting at uc2)
  const int ub = tid >> 3;
  const int uc2 = (tid & 7) * 2;
  float c2[2] = {0.f, 0.f};

  const unsigned short* gbase = gx + jb * 16 + uc2;
  ushort2 gxv[4], rv;
  {
    const unsigned short* g0 = gbase + (size_t)ub * GXW;
    #pragma unroll
    for (int gg = 0; gg < 4; ++gg) gxv[gg] = *(const ushort2*)(g0 + gg * 512);
    rv = *(const ushort2*)(g0 + 2048);
  }

  // Per-lane A-fragment byte offset within a 64KB h slab:
  // row = mh*32 (+ mt*16) + col ; byte = row*1024 + gp*512 + kk*64 + q*16
  const int frag_off = (mh * 32 + col) * 1024 + gp * 512 + q * 16;

  for (int t = 0; t < 512; ++t) {
    if (t > 0) {
      if (tid < 32) {
        while (__hip_atomic_load(flags + tid, __ATOMIC_RELAXED, __HIP_MEMORY_SCOPE_AGENT) < t) {
        }
      }
      __syncthreads();
    }

    // Direct global->register A fragments (coherent): 16 loads back-to-back
    // (one LLC round trip), single drain. No LDS staging.
    v4i a0[8], a1[8];
    {
      const char* hb  = (const char*)hbuf + (t & 1) * 65536 + frag_off;
      const char* hb1 = hb + 16384;   // mt=1 rows (+16*1024)
      #define LDA(dst, base, off) \
        asm volatile("global_load_dwordx4 %0, %1, off offset:" #off " sc0 sc1" \
                     : "=v"(dst) : "v"(base) : "memory");
      LDA(a0[0], hb, 0)    LDA(a0[1], hb, 64)   LDA(a0[2], hb, 128)  LDA(a0[3], hb, 192)
      LDA(a0[4], hb, 256)  LDA(a0[5], hb, 320)  LDA(a0[6], hb, 384)  LDA(a0[7], hb, 448)
      LDA(a1[0], hb1, 0)   LDA(a1[1], hb1, 64)  LDA(a1[2], hb1, 128) LDA(a1[3], hb1, 192)
      LDA(a1[4], hb1, 256) LDA(a1[5], hb1, 320) LDA(a1[6], hb1, 384) LDA(a1[7], hb1, 448)
      #undef LDA
      asm volatile("s_waitcnt vmcnt(0)" ::: "memory");
    }

    // Prefetch gx/res for t+1 NOW (overlaps MFMA/EW/publish; complete long
    // before the next poll's drain).
    ushort2 ngx[4], nrv;
    if (t < 511) {
      const unsigned short* gn = gbase + (size_t)((t + 1) * 64 + ub) * GXW;
      #pragma unroll
      for (int gg = 0; gg < 4; ++gg) ngx[gg] = *(const ushort2*)(gn + gg * 512);
      nrv = *(const ushort2*)(gn + 2048);
    }

    // S[gp][gh*2+g2] += h_{t-1} @ Whx^T  (this wave's quarter)
    f32x4v acc[2][2] = {};
    #pragma unroll
    for (int kk = 0; kk < 8; ++kk) {
      bfrag8 af0 = __builtin_bit_cast(bfrag8, a0[kk]);
      bfrag8 af1 = __builtin_bit_cast(bfrag8, a1[kk]);
      #pragma unroll
      for (int g2 = 0; g2 < 2; ++g2) {
        acc[0][g2] = __builtin_amdgcn_mfma_f32_16x16x32_bf16(af0, Bf[g2][kk], acc[0][g2], 0, 0, 0);
        acc[1][g2] = __builtin_amdgcn_mfma_f32_16x16x32_bf16(af1, Bf[g2][kk], acc[1][g2], 0, 0, 0);
      }
    }

    #pragma unroll
    for (int mt = 0; mt < 2; ++mt)
      #pragma unroll
      for (int g2 = 0; g2 < 2; ++g2) {
        const int gate = gh * 2 + g2;
        const int b0 = mh * 32 + mt * 16 + q * 4;
        #pragma unroll
        for (int r = 0; r < 4; ++r)
          S[gp][gate][b0 + r][col] = acc[mt][g2][r];
      }
    __syncthreads();

    // elementwise gate/update (all 512 threads, 2 cols each): sum K-half partials
    float pre[4][2];
    #pragma unroll
    for (int gg = 0; gg < 4; ++gg) {
      float2 s0 = *(const float2*)&S[0][gg][ub][uc2];
      float2 s1 = *(const float2*)&S[1][gg][ub][uc2];
      pre[gg][0] = s0.x + s1.x + bf2f(gxv[gg].x);
      pre[gg][1] = s0.y + s1.y + bf2f(gxv[gg].y);
    }
    float rr[2] = {bf2f(rv.x), bf2f(rv.y)};
    float hv[2];
    #pragma unroll
    for (int j = 0; j < 2; ++j) {
      float fg = sigf(pre[0][j]);
      float ig = sigf(pre[1][j]);
      float g_ = tanh_f(pre[2][j]);
      float og = sigf(pre[3][j]);
      c2[j] = fg * c2[j] + ig * g_;
      hv[j] = og * tanh_f(c2[j]) + rr[j];
    }

    if (t < 511) {
      // Publish h_t: agent-scope 4B atomic store, drain, barrier, flag.
      unsigned int pk = (unsigned int)f2bf(hv[0]) | ((unsigned int)f2bf(hv[1]) << 16);
      __hip_atomic_store((unsigned int*)(hbuf + ((t + 1) & 1) * 32768 + ub * 512 + jb * 16 + uc2),
                         pk, __ATOMIC_RELAXED, __HIP_MEMORY_SCOPE_AGENT);
      asm volatile("s_waitcnt vmcnt(0)" ::: "memory");
      __syncthreads();
      if (tid == 0)
        __hip_atomic_store(flags + jb, t + 1, __ATOMIC_RELAXED, __HIP_MEMORY_SCOPE_AGENT);
    }

    // Non-critical-path stores after publish.
    *(float2*)(out + (size_t)t * 32768 + ub * 512 + jb * 16 + uc2) = make_float2(hv[0], hv[1]);

    if (t == 511) {
      *(float2*)(out + OUT_HX + ub * 512 + jb * 16 + uc2) = make_float2(hv[0], hv[1]);
      *(float2*)(out + OUT_CX + ub * 512 + jb * 16 + uc2) = make_float2(c2[0], c2[1]);
    } else {
      #pragma unroll
      for (int gg = 0; gg < 4; ++gg) gxv[gg] = ngx[gg];
      rv = nrv;
    }
  }
}

extern "C" void kernel_launch(void* const* d_in, const int* in_sizes, int n_in,
                              void* d_out, int out_size, void* d_ws, size_t ws_size,
                              hipStream_t stream) {
  const float* inputs = (const float*)d_in[0];
  const float* Wf = (const float*)d_in[1];
  const float* bf_ = (const float*)d_in[2];
  const float* Wi = (const float*)d_in[3];
  const float* bi_ = (const float*)d_in[4];
  const float* Wg = (const float*)d_in[5];
  const float* bg_ = (const float*)d_in[6];
  const float* Wo = (const float*)d_in[7];
  const float* bo_ = (const float*)d_in[8];
  const float* Wr = (const float*)d_in[9];
  const float* br_ = (const float*)d_in[10];
  float* out = (float*)d_out;

  // workspace layout (all 16B-aligned)
  unsigned short* X    = (unsigned short*)d_ws;        // 16777216 el
  unsigned short* Wc   = X + 16777216;                 // 1310720 el
  unsigned short* Whx  = Wc + 1310720;                 // 1048576 el
  float*          bias = (float*)(Whx + 1048576);      // 2560 el
  unsigned short* gx   = (unsigned short*)(bias + 2560);  // 83886080 el
  unsigned short* hbuf = gx + 83886080;                // 65536 el
  int*            flags = (int*)(hbuf + 65536);        // 32 el
  const size_t ws_needed = 206186624;
  if (ws_size < ws_needed) return;   // fail visibly rather than corrupt

  hipMemsetAsync(hbuf, 0, 65536 * 2 + 32 * 4, stream);   // h0 = 0 (both slots), flags = 0

  cvt_kernel<<<16384, 256, 0, stream>>>(inputs, X);
  repack_kernel<<<1280, 256, 0, stream>>>(Wf, Wi, Wg, Wo, Wr, bf_, bi_, bg_, bo_, br_,
                                          Wc, Whx, bias);
  gemm_kernel<<<dim3(20, 256), 256, 0, stream>>>(Wc, X, bias, gx);
  recur_kernel<<<32, 512, 0, stream>>>(Whx, gx, hbuf, flags, out);
}